// Round 1
// baseline (209.937 us; speedup 1.0000x reference)
//
#include <hip/hip_runtime.h>
#include <hip/hip_bf16.h>
#include <math.h>

typedef __attribute__((ext_vector_type(8))) short short8;
typedef __attribute__((ext_vector_type(4))) float f32x4;
typedef unsigned short u16b;

#define DEV __device__ __forceinline__

static constexpr int NB = 4, LSEQ = 4096, DMODEL = 128, DE = 256, DN = 16;
static constexpr int NTOK = NB * LSEQ;              // 16384
static constexpr int LCH = 128, NCHK = LSEQ / LCH;  // 128-step chunks, 32/batch

DEV float bfu2f(u16b u) { union { unsigned int i; float f; } x; x.i = ((unsigned int)u) << 16; return x.f; }
DEV u16b f2bfu(float f) {
  union { float fv; unsigned int i; } x; x.fv = f;
  unsigned int r = x.i + 0x7fffu + ((x.i >> 16) & 1u);
  return (u16b)(r >> 16);
}

// ---------------- prep kernels (weight massage, run every call; deterministic) ----------------
__global__ __launch_bounds__(256) void k_prep1(
    const float* __restrict__ xp, const float* __restrict__ dtw,
    const float* __restrict__ A_log, float* __restrict__ M2, float* __restrict__ Al2) {
  int tid = blockIdx.x * 256 + threadIdx.x;  // 65536
  int n = tid & 255, k = tid >> 8;
  float acc = 0.f;
#pragma unroll
  for (int r = 0; r < 8; ++r) acc += xp[k * 40 + r] * dtw[r * 256 + n];
  M2[k * 256 + n] = acc;
  if (tid < DE * DN) Al2[tid] = -expf(A_log[tid]) * 1.44269504088896341f;  // A * log2(e)
}

__global__ __launch_bounds__(256) void k_prep2(
    const float* __restrict__ conv_w, const float* __restrict__ in_w,
    const float* __restrict__ M2, const float* __restrict__ xp,
    const float* __restrict__ out_w,
    u16b* __restrict__ Wc, u16b* __restrict__ Wi, u16b* __restrict__ Wx, u16b* __restrict__ Wo) {
  int tid = blockIdx.x * 256 + threadIdx.x;  // 27648 tasks
  short8 sv;
  if (tid < 6144) {            // conv Bmat: [48][128][8]; Bmat[kk*128+ci][co] = conv_w[co][ci][kk]
    int kg = tid >> 7, n = tid & 127;
#pragma unroll
    for (int j = 0; j < 8; ++j) {
      int kidx = kg * 8 + j, kk = kidx >> 7, ci = kidx & 127;
      sv[j] = (short)f2bfu(conv_w[(n * 128 + ci) * 3 + kk]);
    }
    *reinterpret_cast<short8*>(&Wc[(kg * 128 + n) * 8]) = sv;
  } else if (tid < 14336) {    // in_proj: [16][512][8]
    int t = tid - 6144; int kg = t >> 9, n = t & 511;
#pragma unroll
    for (int j = 0; j < 8; ++j) sv[j] = (short)f2bfu(in_w[(kg * 8 + j) * 512 + n]);
    *reinterpret_cast<short8*>(&Wi[(kg * 512 + n) * 8]) = sv;
  } else if (tid < 23552) {    // x_proj fused: [32][288][8] : cols 0..255 = M2, 256..287 = Wx[:,8:40]
    int t = tid - 14336; int kg = t / 288, n = t % 288;
#pragma unroll
    for (int j = 0; j < 8; ++j) {
      int k = kg * 8 + j;
      sv[j] = (short)f2bfu(n < 256 ? M2[k * 256 + n] : xp[k * 40 + 8 + (n - 256)]);
    }
    *reinterpret_cast<short8*>(&Wx[(kg * 288 + n) * 8]) = sv;
  } else if (tid < 27648) {    // out_proj: [32][128][8]
    int t = tid - 23552; int kg = t >> 7, n = t & 127;
#pragma unroll
    for (int j = 0; j < 8; ++j) sv[j] = (short)f2bfu(out_w[(kg * 8 + j) * 128 + n]);
    *reinterpret_cast<short8*>(&Wo[(kg * 128 + n) * 8]) = sv;
  }
}

// ---------------- LayerNorm: one wave per token ----------------
__global__ __launch_bounds__(256) void k_ln(
    const float* __restrict__ x, const float* __restrict__ g, const float* __restrict__ b,
    u16b* __restrict__ h) {
  int wv = (blockIdx.x * 256 + threadIdx.x) >> 6;  // token
  int l = threadIdx.x & 63;
  float2 xv = *reinterpret_cast<const float2*>(&x[(size_t)wv * 128 + l * 2]);
  float s = xv.x + xv.y, s2 = xv.x * xv.x + xv.y * xv.y;
#pragma unroll
  for (int m = 1; m < 64; m <<= 1) { s += __shfl_xor(s, m, 64); s2 += __shfl_xor(s2, m, 64); }
  float mu = s * (1.f / 128.f);
  float var = s2 * (1.f / 128.f) - mu * mu;
  float inv = rsqrtf(var + 1e-5f);
  u16b o0 = f2bfu((xv.x - mu) * inv * g[l * 2] + b[l * 2]);
  u16b o1 = f2bfu((xv.y - mu) * inv * g[l * 2 + 1] + b[l * 2 + 1]);
  u16b* hp = &h[(size_t)wv * 128 + l * 2];
  hp[0] = o0; hp[1] = o1;
}

// ---------------- generic MFMA core: BM=64 rows x BN cols, A row-major (stride K), B pre-swizzled [K/8][Ntot][8]
template <int K, int BN>
DEV void gemm_core(const u16b* __restrict__ Asrc, const u16b* __restrict__ Bsw, int Ntot,
                   int t0, int n0, u16b* a_lds, u16b* b_lds, f32x4* acc) {
  constexpr int LDA = K + 8;
  const int tid = threadIdx.x;
  for (int idx = tid; idx < 64 * (K / 8); idx += 256) {
    int r = idx / (K / 8), kc = idx % (K / 8);
    *reinterpret_cast<uint4*>(&a_lds[r * LDA + kc * 8]) =
        *reinterpret_cast<const uint4*>(&Asrc[(size_t)(t0 + r) * K + kc * 8]);
  }
  for (int idx = tid; idx < (K / 8) * BN; idx += 256) {
    int kg = idx / BN, nn = idx % BN;
    *reinterpret_cast<uint4*>(&b_lds[(kg * BN + nn) * 8]) =
        *reinterpret_cast<const uint4*>(&Bsw[((size_t)kg * Ntot + n0 + nn) * 8]);
  }
  __syncthreads();
  const int w = tid >> 6, l = tid & 63;
  const int lr = l & 15, lk = l >> 4;
#pragma unroll
  for (int nt = 0; nt < BN / 16; ++nt) acc[nt] = f32x4{0.f, 0.f, 0.f, 0.f};
#pragma unroll
  for (int c = 0; c < K / 32; ++c) {
    short8 af = *reinterpret_cast<const short8*>(&a_lds[(w * 16 + lr) * LDA + c * 32 + lk * 8]);
#pragma unroll
    for (int nt = 0; nt < BN / 16; ++nt) {
      short8 bf = *reinterpret_cast<const short8*>(&b_lds[((c * 4 + lk) * BN + nt * 16 + lr) * 8]);
      acc[nt] = __builtin_amdgcn_mfma_f32_16x16x32_bf16(af, bf, acc[nt], 0, 0, 0);
    }
  }
}

// ---------------- block conv (K=3, full 128x128) as GEMM over haloed h tile + exact GELU ----------------
__global__ __launch_bounds__(256) void k_convgemm(
    const u16b* __restrict__ h, const u16b* __restrict__ Bsw,
    const float* __restrict__ convb, u16b* __restrict__ hconv) {
  __shared__ __align__(16) u16b h_lds[66 * 136];
  __shared__ __align__(16) u16b b_lds[48 * 64 * 8];
  const int t0 = blockIdx.x * 64, n0 = blockIdx.y * 64;
  const int tl0 = t0 & (LSEQ - 1);
  const int tid = threadIdx.x;
  for (int idx = tid; idx < 66 * 16; idx += 256) {  // rows t0-2 .. t0+63
    int r = idx >> 4, kc = idx & 15;
    uint4 v = make_uint4(0u, 0u, 0u, 0u);
    if (tl0 + r - 2 >= 0)
      v = *reinterpret_cast<const uint4*>(&h[(size_t)(t0 + r - 2) * 128 + kc * 8]);
    *reinterpret_cast<uint4*>(&h_lds[r * 136 + kc * 8]) = v;
  }
  for (int idx = tid; idx < 48 * 64; idx += 256) {
    int kg = idx >> 6, nn = idx & 63;
    *reinterpret_cast<uint4*>(&b_lds[(kg * 64 + nn) * 8]) =
        *reinterpret_cast<const uint4*>(&Bsw[((size_t)kg * 128 + n0 + nn) * 8]);
  }
  __syncthreads();
  const int w = tid >> 6, l = tid & 63, lr = l & 15, lk = l >> 4;
  f32x4 acc[4];
#pragma unroll
  for (int nt = 0; nt < 4; ++nt) acc[nt] = f32x4{0.f, 0.f, 0.f, 0.f};
#pragma unroll
  for (int c = 0; c < 12; ++c) {
    int kk = c >> 2, ci0 = (c & 3) * 32;
    short8 af = *reinterpret_cast<const short8*>(&h_lds[(w * 16 + lr + kk) * 136 + ci0 + lk * 8]);
#pragma unroll
    for (int nt = 0; nt < 4; ++nt) {
      short8 bf = *reinterpret_cast<const short8*>(&b_lds[((c * 4 + lk) * 64 + nt * 16 + lr) * 8]);
      acc[nt] = __builtin_amdgcn_mfma_f32_16x16x32_bf16(af, bf, acc[nt], 0, 0, 0);
    }
  }
  const int rbase = t0 + w * 16 + lk * 4, cb = n0 + lr;
#pragma unroll
  for (int nt = 0; nt < 4; ++nt)
#pragma unroll
    for (int r = 0; r < 4; ++r) {
      int row = rbase + r, col = cb + nt * 16;
      float v = acc[nt][r] + convb[col];
      float gel = 0.5f * v * (1.f + erff(v * 0.70710678118654752f));
      hconv[(size_t)row * 128 + col] = f2bfu(gel);
    }
}

// ---------------- in_proj: (BL,128)@(128,512), split x_in / z ----------------
__global__ __launch_bounds__(256) void k_inproj(
    const u16b* __restrict__ h, const u16b* __restrict__ Bsw, const float* __restrict__ bias,
    u16b* __restrict__ xin, u16b* __restrict__ zbuf) {
  __shared__ __align__(16) u16b a_lds[64 * 136];
  __shared__ __align__(16) u16b b_lds[16 * 64 * 8];
  f32x4 acc[4];
  const int t0 = blockIdx.x * 64, n0 = blockIdx.y * 64;
  gemm_core<128, 64>(h, Bsw, 512, t0, n0, a_lds, b_lds, acc);
  const int w = threadIdx.x >> 6, l = threadIdx.x & 63;
  const int rbase = t0 + w * 16 + (l >> 4) * 4, cb = n0 + (l & 15);
#pragma unroll
  for (int nt = 0; nt < 4; ++nt)
#pragma unroll
    for (int r = 0; r < 4; ++r) {
      int row = rbase + r, col = cb + nt * 16;
      float v = acc[nt][r] + bias[col];
      if (col < 256) xin[(size_t)row * 256 + col] = f2bfu(v);
      else zbuf[(size_t)row * 256 + (col - 256)] = f2bfu(v);
    }
}

// ---------------- depthwise causal conv (k=4) + SiLU ----------------
__global__ __launch_bounds__(256) void k_dwconv(
    const u16b* __restrict__ xin, const float* __restrict__ w1, const float* __restrict__ b1,
    u16b* __restrict__ xconv) {
  int idx = blockIdx.x * 256 + threadIdx.x;  // over NTOK*256
  int e = idx & 255, t = idx >> 8, tl = t & (LSEQ - 1);
  float acc = b1[e];
#pragma unroll
  for (int k = 0; k < 4; ++k) {
    int tt = tl - 3 + k;
    if (tt >= 0) acc += bfu2f(xin[(size_t)(t - 3 + k) * 256 + e]) * w1[e * 4 + k];
  }
  float s = acc / (1.f + __expf(-acc));  // SiLU
  xconv[(size_t)t * 256 + e] = f2bfu(s);
}

// ---------------- x_proj fused with dt_proj: (BL,256)@(256,288) -> dt(sp) | B | C ----------------
__global__ __launch_bounds__(256) void k_xproj(
    const u16b* __restrict__ xconv, const u16b* __restrict__ Bsw, const float* __restrict__ dtb,
    float* __restrict__ dt, float* __restrict__ Bm, float* __restrict__ Cm) {
  __shared__ __align__(16) u16b a_lds[64 * 264];
  __shared__ __align__(16) u16b b_lds[32 * 48 * 8];
  f32x4 acc[3];
  const int t0 = blockIdx.x * 64, n0 = blockIdx.y * 48;
  gemm_core<256, 48>(xconv, Bsw, 288, t0, n0, a_lds, b_lds, acc);
  const int w = threadIdx.x >> 6, l = threadIdx.x & 63;
  const int rbase = t0 + w * 16 + (l >> 4) * 4, cb = n0 + (l & 15);
#pragma unroll
  for (int nt = 0; nt < 3; ++nt)
#pragma unroll
    for (int r = 0; r < 4; ++r) {
      int row = rbase + r, col = cb + nt * 16;
      float v = acc[nt][r];
      if (col < 256) {
        float val = v + dtb[col];
        dt[(size_t)row * 256 + col] = (val > 20.f) ? val : log1pf(__expf(val));  // softplus
      } else if (col < 272) {
        Bm[(size_t)row * 16 + (col - 256)] = v;
      } else {
        Cm[(size_t)row * 16 + (col - 272)] = v;
      }
    }
}

// ---------------- selective scan, chunked: pass1 (P = prod dA, h_local) ----------------
__global__ __launch_bounds__(256) void k_scan1(
    const float* __restrict__ dt, const u16b* __restrict__ u, const float* __restrict__ Bm,
    const float* __restrict__ Al2, float* __restrict__ Pst, float* __restrict__ Hst) {
  __shared__ float dt_s[LCH * 16], u_s[LCH * 16], b_s[LCH * 16];
  const int bid = blockIdx.x;
  const int eg = bid & 15, c = (bid >> 4) & 31, b = bid >> 9;
  const int e0 = eg * 16;
  const size_t base = (size_t)b * LSEQ + (size_t)c * LCH;
  for (int idx = threadIdx.x; idx < LCH * 16; idx += 256) {
    int t = idx >> 4, ei = idx & 15;
    dt_s[idx] = dt[(base + t) * DE + e0 + ei];
    u_s[idx] = bfu2f(u[(base + t) * DE + e0 + ei]);
    b_s[idx] = Bm[(base + t) * DN + ei];
  }
  __syncthreads();
  const int w = threadIdx.x >> 6, l = threadIdx.x & 63;
  const int esub = w * 4 + (l >> 4), n = l & 15;
  const float coef = Al2[(e0 + esub) * 16 + n];
  float h = 0.f, P = 1.f;
  for (int t = 0; t < LCH; ++t) {
    float dtv = dt_s[t * 16 + esub];
    float a = exp2f(dtv * coef);
    float bu = dtv * b_s[t * 16 + n] * u_s[t * 16 + esub];
    h = fmaf(a, h, bu);
    P *= a;
  }
  size_t o = (((size_t)b * NCHK + c) * DE + e0 + esub) * DN + n;
  Pst[o] = P; Hst[o] = h;
}

// ---------------- cross-chunk combine (sequential over 32 chunks) ----------------
__global__ __launch_bounds__(256) void k_combine(
    const float* __restrict__ Pst, const float* __restrict__ Hst, float* __restrict__ Hin) {
  int idx = blockIdx.x * 256 + threadIdx.x;  // over NB*DE*DN = 16384
  int en = idx & (DE * DN - 1), b = idx >> 12;
  float h = 0.f;
  for (int c = 0; c < NCHK; ++c) {
    size_t o = ((size_t)b * NCHK + c) * (DE * DN) + en;
    Hin[o] = h;
    h = fmaf(Pst[o], h, Hst[o]);
  }
}

// ---------------- pass2: replay chunk from Hin, y = C·h + u*D, out yz = y * silu(z) ----------------
__global__ __launch_bounds__(256) void k_scan2(
    const float* __restrict__ dt, const u16b* __restrict__ u, const float* __restrict__ Bm,
    const float* __restrict__ Cm, const float* __restrict__ Al2, const float* __restrict__ Hin,
    const float* __restrict__ Dsk, const u16b* __restrict__ zbuf, u16b* __restrict__ yz) {
  __shared__ float dt_s[LCH * 16], u_s[LCH * 16], b_s[LCH * 16], c_s[LCH * 16], y_s[LCH * 16];
  const int bid = blockIdx.x;
  const int eg = bid & 15, c = (bid >> 4) & 31, b = bid >> 9;
  const int e0 = eg * 16;
  const size_t base = (size_t)b * LSEQ + (size_t)c * LCH;
  for (int idx = threadIdx.x; idx < LCH * 16; idx += 256) {
    int t = idx >> 4, ei = idx & 15;
    dt_s[idx] = dt[(base + t) * DE + e0 + ei];
    u_s[idx] = bfu2f(u[(base + t) * DE + e0 + ei]);
    b_s[idx] = Bm[(base + t) * DN + ei];
    c_s[idx] = Cm[(base + t) * DN + ei];
  }
  __syncthreads();
  const int w = threadIdx.x >> 6, l = threadIdx.x & 63;
  const int esub = w * 4 + (l >> 4), n = l & 15;
  const float coef = Al2[(e0 + esub) * 16 + n];
  const float dskv = Dsk[e0 + esub];
  size_t o = (((size_t)b * NCHK + c) * DE + e0 + esub) * DN + n;
  float h = Hin[o];
  for (int t = 0; t < LCH; ++t) {
    float dtv = dt_s[t * 16 + esub];
    float a = exp2f(dtv * coef);
    float bu = dtv * b_s[t * 16 + n] * u_s[t * 16 + esub];
    h = fmaf(a, h, bu);
    float y = h * c_s[t * 16 + n];
    y += __shfl_xor(y, 1, 16);
    y += __shfl_xor(y, 2, 16);
    y += __shfl_xor(y, 4, 16);
    y += __shfl_xor(y, 8, 16);
    if (n == 0) y_s[t * 16 + esub] = fmaf(u_s[t * 16 + esub], dskv, y);
  }
  __syncthreads();
  for (int idx = threadIdx.x; idx < LCH * 16; idx += 256) {
    int t = idx >> 4, ei = idx & 15;
    float z = bfu2f(zbuf[(base + t) * DE + e0 + ei]);
    float sz = z / (1.f + __expf(-z));
    yz[(base + t) * DE + e0 + ei] = f2bfu(y_s[idx] * sz);
  }
}

// ---------------- out_proj + final residual combine ----------------
__global__ __launch_bounds__(256) void k_outproj(
    const u16b* __restrict__ yz, const u16b* __restrict__ Bsw, const float* __restrict__ ob,
    const float* __restrict__ x, const u16b* __restrict__ hconv, float* __restrict__ outp) {
  __shared__ __align__(16) u16b a_lds[64 * 264];
  __shared__ __align__(16) u16b b_lds[32 * 64 * 8];
  f32x4 acc[4];
  const int t0 = blockIdx.x * 64, n0 = blockIdx.y * 64;
  gemm_core<256, 64>(yz, Bsw, 128, t0, n0, a_lds, b_lds, acc);
  const int w = threadIdx.x >> 6, l = threadIdx.x & 63;
  const int rbase = t0 + w * 16 + (l >> 4) * 4, cb = n0 + (l & 15);
#pragma unroll
  for (int nt = 0; nt < 4; ++nt)
#pragma unroll
    for (int r = 0; r < 4; ++r) {
      int row = rbase + r, col = cb + nt * 16;
      size_t off = (size_t)row * 128 + col;
      float v = x[off] + 0.5f * (acc[nt][r] + ob[col]) + 0.5f * bfu2f(hconv[off]);
      outp[off] = v;
    }
}

// ---------------- host launch ----------------
extern "C" void kernel_launch(void* const* d_in, const int* in_sizes, int n_in,
                              void* d_out, int out_size, void* d_ws, size_t ws_size,
                              hipStream_t stream) {
  const float* x       = (const float*)d_in[0];
  const float* ln_g    = (const float*)d_in[1];
  const float* ln_b    = (const float*)d_in[2];
  const float* conv_w  = (const float*)d_in[3];
  const float* conv_b  = (const float*)d_in[4];
  const float* in_w    = (const float*)d_in[5];
  const float* in_b    = (const float*)d_in[6];
  const float* dw_w    = (const float*)d_in[7];
  const float* dw_b    = (const float*)d_in[8];
  const float* xp_w    = (const float*)d_in[9];
  const float* dt_w    = (const float*)d_in[10];
  const float* dt_b    = (const float*)d_in[11];
  const float* A_log   = (const float*)d_in[12];
  const float* Dskip   = (const float*)d_in[13];
  const float* out_w   = (const float*)d_in[14];
  const float* out_b   = (const float*)d_in[15];
  float* outp = (float*)d_out;

  char* ws = (char*)d_ws;
  size_t off = 0;
  auto alloc = [&](size_t bytes) { char* p = ws + off; off += bytes; return p; };
  float* Al2   = (float*)alloc(4096ull * 4);              // A * log2e
  float* M2    = (float*)alloc(65536ull * 4);             // Wx[:, :8] @ Wdt
  u16b* WcSw   = (u16b*)alloc(49152ull * 2);              // conv  [48][128][8]
  u16b* WiSw   = (u16b*)alloc(65536ull * 2);              // inprj [16][512][8]
  u16b* WxSw   = (u16b*)alloc(73728ull * 2);              // xproj [32][288][8]
  u16b* WoSw   = (u16b*)alloc(32768ull * 2);              // outprj[32][128][8]
  u16b* hbuf   = (u16b*)alloc((size_t)NTOK * 128 * 2);    // LN output
  u16b* hconv  = (u16b*)alloc((size_t)NTOK * 128 * 2);    // gelu(conv)
  u16b* xin    = (u16b*)alloc((size_t)NTOK * 256 * 2);
  u16b* zbuf   = (u16b*)alloc((size_t)NTOK * 256 * 2);
  u16b* xconv  = (u16b*)alloc((size_t)NTOK * 256 * 2);    // u for scan
  float* dt    = (float*)alloc((size_t)NTOK * 256 * 4);   // softplus'd
  float* Bm    = (float*)alloc((size_t)NTOK * 16 * 4);
  float* Cm    = (float*)alloc((size_t)NTOK * 16 * 4);
  float* Pst   = (float*)alloc(524288ull * 4);
  float* Hst   = (float*)alloc(524288ull * 4);
  float* Hin   = (float*)alloc(524288ull * 4);
  u16b* yz     = (u16b*)alloc((size_t)NTOK * 256 * 2);
  (void)ws_size; (void)in_sizes; (void)n_in; (void)out_size;

  k_prep1<<<256, 256, 0, stream>>>(xp_w, dt_w, A_log, M2, Al2);
  k_prep2<<<108, 256, 0, stream>>>(conv_w, in_w, M2, xp_w, out_w, WcSw, WiSw, WxSw, WoSw);
  k_ln<<<NTOK / 4, 256, 0, stream>>>(x, ln_g, ln_b, hbuf);
  k_convgemm<<<dim3(NTOK / 64, 2), 256, 0, stream>>>(hbuf, WcSw, conv_b, hconv);
  k_inproj<<<dim3(NTOK / 64, 8), 256, 0, stream>>>(hbuf, WiSw, in_b, xin, zbuf);
  k_dwconv<<<(NTOK * 256) / 256, 256, 0, stream>>>(xin, dw_w, dw_b, xconv);
  k_xproj<<<dim3(NTOK / 64, 6), 256, 0, stream>>>(xconv, WxSw, dt_b, dt, Bm, Cm);
  k_scan1<<<NB * NCHK * 16, 256, 0, stream>>>(dt, xconv, Bm, Al2, Pst, Hst);
  k_combine<<<64, 256, 0, stream>>>(Pst, Hst, Hin);
  k_scan2<<<NB * NCHK * 16, 256, 0, stream>>>(dt, xconv, Bm, Cm, Al2, Hin, Dskip, zbuf, yz);
  k_outproj<<<dim3(NTOK / 64, 2), 256, 0, stream>>>(yz, WoSw, out_b, x, hconv, outp);
}

// Round 2
// 179.821 us; speedup vs baseline: 1.1675x; 1.1675x over previous
//
#include <hip/hip_runtime.h>
#include <hip/hip_bf16.h>
#include <math.h>

typedef __attribute__((ext_vector_type(8))) short short8;
typedef __attribute__((ext_vector_type(4))) float f32x4;
typedef unsigned short u16b;

#define DEV __device__ __forceinline__

static constexpr int NB = 4, LSEQ = 4096, DMODEL = 128, DE = 256, DN = 16;
static constexpr int NTOK = NB * LSEQ;              // 16384
static constexpr int LCH = 32, NCHK = LSEQ / LCH;   // 32-step chunks, 128/batch

DEV float bfu2f(u16b u) { union { unsigned int i; float f; } x; x.i = ((unsigned int)u) << 16; return x.f; }
DEV u16b f2bfu(float f) {
  union { float fv; unsigned int i; } x; x.fv = f;
  unsigned int r = x.i + 0x7fffu + ((x.i >> 16) & 1u);
  return (u16b)(r >> 16);
}

// ---------------- prep kernels (weight massage, run every call; deterministic) ----------------
__global__ __launch_bounds__(256) void k_prep1(
    const float* __restrict__ xp, const float* __restrict__ dtw,
    const float* __restrict__ A_log, float* __restrict__ M2, float* __restrict__ Al2) {
  int tid = blockIdx.x * 256 + threadIdx.x;  // 65536
  int n = tid & 255, k = tid >> 8;
  float acc = 0.f;
#pragma unroll
  for (int r = 0; r < 8; ++r) acc += xp[k * 40 + r] * dtw[r * 256 + n];
  M2[k * 256 + n] = acc;
  if (tid < DE * DN) Al2[tid] = -expf(A_log[tid]) * 1.44269504088896341f;  // A * log2(e)
}

__global__ __launch_bounds__(256) void k_prep2(
    const float* __restrict__ conv_w, const float* __restrict__ in_w,
    const float* __restrict__ M2, const float* __restrict__ xp,
    const float* __restrict__ out_w,
    u16b* __restrict__ Wc, u16b* __restrict__ Wi, u16b* __restrict__ Wx, u16b* __restrict__ Wo) {
  int tid = blockIdx.x * 256 + threadIdx.x;  // 27648 tasks
  short8 sv;
  if (tid < 6144) {            // conv Bmat: [48][128][8]; Bmat[kk*128+ci][co] = conv_w[co][ci][kk]
    int kg = tid >> 7, n = tid & 127;
#pragma unroll
    for (int j = 0; j < 8; ++j) {
      int kidx = kg * 8 + j, kk = kidx >> 7, ci = kidx & 127;
      sv[j] = (short)f2bfu(conv_w[(n * 128 + ci) * 3 + kk]);
    }
    *reinterpret_cast<short8*>(&Wc[(kg * 128 + n) * 8]) = sv;
  } else if (tid < 14336) {    // in_proj: [16][512][8]
    int t = tid - 6144; int kg = t >> 9, n = t & 511;
#pragma unroll
    for (int j = 0; j < 8; ++j) sv[j] = (short)f2bfu(in_w[(kg * 8 + j) * 512 + n]);
    *reinterpret_cast<short8*>(&Wi[(kg * 512 + n) * 8]) = sv;
  } else if (tid < 23552) {    // x_proj fused: [32][288][8] : cols 0..255 = M2, 256..287 = Wx[:,8:40]
    int t = tid - 14336; int kg = t / 288, n = t % 288;
#pragma unroll
    for (int j = 0; j < 8; ++j) {
      int k = kg * 8 + j;
      sv[j] = (short)f2bfu(n < 256 ? M2[k * 256 + n] : xp[k * 40 + 8 + (n - 256)]);
    }
    *reinterpret_cast<short8*>(&Wx[(kg * 288 + n) * 8]) = sv;
  } else if (tid < 27648) {    // out_proj: [32][128][8]
    int t = tid - 23552; int kg = t >> 7, n = t & 127;
#pragma unroll
    for (int j = 0; j < 8; ++j) sv[j] = (short)f2bfu(out_w[(kg * 8 + j) * 128 + n]);
    *reinterpret_cast<short8*>(&Wo[(kg * 128 + n) * 8]) = sv;
  }
}

// ---------------- LayerNorm: one wave per token ----------------
__global__ __launch_bounds__(256) void k_ln(
    const float* __restrict__ x, const float* __restrict__ g, const float* __restrict__ b,
    u16b* __restrict__ h) {
  int wv = (blockIdx.x * 256 + threadIdx.x) >> 6;  // token
  int l = threadIdx.x & 63;
  float2 xv = *reinterpret_cast<const float2*>(&x[(size_t)wv * 128 + l * 2]);
  float s = xv.x + xv.y, s2 = xv.x * xv.x + xv.y * xv.y;
#pragma unroll
  for (int m = 1; m < 64; m <<= 1) { s += __shfl_xor(s, m, 64); s2 += __shfl_xor(s2, m, 64); }
  float mu = s * (1.f / 128.f);
  float var = s2 * (1.f / 128.f) - mu * mu;
  float inv = rsqrtf(var + 1e-5f);
  u16b o0 = f2bfu((xv.x - mu) * inv * g[l * 2] + b[l * 2]);
  u16b o1 = f2bfu((xv.y - mu) * inv * g[l * 2 + 1] + b[l * 2 + 1]);
  u16b* hp = &h[(size_t)wv * 128 + l * 2];
  hp[0] = o0; hp[1] = o1;
}

// ---------------- generic MFMA core: BM=64 rows x BN cols, A row-major (stride K), B pre-swizzled [K/8][Ntot][8]
template <int K, int BN>
DEV void gemm_core(const u16b* __restrict__ Asrc, const u16b* __restrict__ Bsw, int Ntot,
                   int t0, int n0, u16b* a_lds, u16b* b_lds, f32x4* acc) {
  constexpr int LDA = K + 8;
  const int tid = threadIdx.x;
  for (int idx = tid; idx < 64 * (K / 8); idx += 256) {
    int r = idx / (K / 8), kc = idx % (K / 8);
    *reinterpret_cast<uint4*>(&a_lds[r * LDA + kc * 8]) =
        *reinterpret_cast<const uint4*>(&Asrc[(size_t)(t0 + r) * K + kc * 8]);
  }
  for (int idx = tid; idx < (K / 8) * BN; idx += 256) {
    int kg = idx / BN, nn = idx % BN;
    *reinterpret_cast<uint4*>(&b_lds[(kg * BN + nn) * 8]) =
        *reinterpret_cast<const uint4*>(&Bsw[((size_t)kg * Ntot + n0 + nn) * 8]);
  }
  __syncthreads();
  const int w = tid >> 6, l = tid & 63;
  const int lr = l & 15, lk = l >> 4;
#pragma unroll
  for (int nt = 0; nt < BN / 16; ++nt) acc[nt] = f32x4{0.f, 0.f, 0.f, 0.f};
#pragma unroll
  for (int c = 0; c < K / 32; ++c) {
    short8 af = *reinterpret_cast<const short8*>(&a_lds[(w * 16 + lr) * LDA + c * 32 + lk * 8]);
#pragma unroll
    for (int nt = 0; nt < BN / 16; ++nt) {
      short8 bf = *reinterpret_cast<const short8*>(&b_lds[((c * 4 + lk) * BN + nt * 16 + lr) * 8]);
      acc[nt] = __builtin_amdgcn_mfma_f32_16x16x32_bf16(af, bf, acc[nt], 0, 0, 0);
    }
  }
}

// ---------------- block conv (K=3, full 128x128) as GEMM over haloed h tile + exact GELU ----------------
__global__ __launch_bounds__(256) void k_convgemm(
    const u16b* __restrict__ h, const u16b* __restrict__ Bsw,
    const float* __restrict__ convb, u16b* __restrict__ hconv) {
  __shared__ __align__(16) u16b h_lds[66 * 136];
  __shared__ __align__(16) u16b b_lds[48 * 64 * 8];
  const int t0 = blockIdx.x * 64, n0 = blockIdx.y * 64;
  const int tl0 = t0 & (LSEQ - 1);
  const int tid = threadIdx.x;
  for (int idx = tid; idx < 66 * 16; idx += 256) {  // rows t0-2 .. t0+63
    int r = idx >> 4, kc = idx & 15;
    uint4 v = make_uint4(0u, 0u, 0u, 0u);
    if (tl0 + r - 2 >= 0)
      v = *reinterpret_cast<const uint4*>(&h[(size_t)(t0 + r - 2) * 128 + kc * 8]);
    *reinterpret_cast<uint4*>(&h_lds[r * 136 + kc * 8]) = v;
  }
  for (int idx = tid; idx < 48 * 64; idx += 256) {
    int kg = idx >> 6, nn = idx & 63;
    *reinterpret_cast<uint4*>(&b_lds[(kg * 64 + nn) * 8]) =
        *reinterpret_cast<const uint4*>(&Bsw[((size_t)kg * 128 + n0 + nn) * 8]);
  }
  __syncthreads();
  const int w = tid >> 6, l = tid & 63, lr = l & 15, lk = l >> 4;
  f32x4 acc[4];
#pragma unroll
  for (int nt = 0; nt < 4; ++nt) acc[nt] = f32x4{0.f, 0.f, 0.f, 0.f};
#pragma unroll
  for (int c = 0; c < 12; ++c) {
    int kk = c >> 2, ci0 = (c & 3) * 32;
    short8 af = *reinterpret_cast<const short8*>(&h_lds[(w * 16 + lr + kk) * 136 + ci0 + lk * 8]);
#pragma unroll
    for (int nt = 0; nt < 4; ++nt) {
      short8 bf = *reinterpret_cast<const short8*>(&b_lds[((c * 4 + lk) * 64 + nt * 16 + lr) * 8]);
      acc[nt] = __builtin_amdgcn_mfma_f32_16x16x32_bf16(af, bf, acc[nt], 0, 0, 0);
    }
  }
  const int rbase = t0 + w * 16 + lk * 4, cb = n0 + lr;
#pragma unroll
  for (int nt = 0; nt < 4; ++nt)
#pragma unroll
    for (int r = 0; r < 4; ++r) {
      int row = rbase + r, col = cb + nt * 16;
      float v = acc[nt][r] + convb[col];
      float gel = 0.5f * v * (1.f + erff(v * 0.70710678118654752f));
      hconv[(size_t)row * 128 + col] = f2bfu(gel);
    }
}

// ---------------- in_proj: (BL,128)@(128,512), split x_in / z ----------------
__global__ __launch_bounds__(256) void k_inproj(
    const u16b* __restrict__ h, const u16b* __restrict__ Bsw, const float* __restrict__ bias,
    u16b* __restrict__ xin, u16b* __restrict__ zbuf) {
  __shared__ __align__(16) u16b a_lds[64 * 136];
  __shared__ __align__(16) u16b b_lds[16 * 64 * 8];
  f32x4 acc[4];
  const int t0 = blockIdx.x * 64, n0 = blockIdx.y * 64;
  gemm_core<128, 64>(h, Bsw, 512, t0, n0, a_lds, b_lds, acc);
  const int w = threadIdx.x >> 6, l = threadIdx.x & 63;
  const int rbase = t0 + w * 16 + (l >> 4) * 4, cb = n0 + (l & 15);
#pragma unroll
  for (int nt = 0; nt < 4; ++nt)
#pragma unroll
    for (int r = 0; r < 4; ++r) {
      int row = rbase + r, col = cb + nt * 16;
      float v = acc[nt][r] + bias[col];
      if (col < 256) xin[(size_t)row * 256 + col] = f2bfu(v);
      else zbuf[(size_t)row * 256 + (col - 256)] = f2bfu(v);
    }
}

// ---------------- depthwise causal conv (k=4) + SiLU, 8 channels/thread ----------------
__global__ __launch_bounds__(256) void k_dwconv(
    const u16b* __restrict__ xin, const float* __restrict__ w1, const float* __restrict__ b1,
    u16b* __restrict__ xconv) {
  int idx = blockIdx.x * 256 + threadIdx.x;  // over NTOK*32
  int eg = idx & 31, t = idx >> 5, tl = t & (LSEQ - 1);
  int e0 = eg * 8;
  float acc[8];
#pragma unroll
  for (int j = 0; j < 8; ++j) acc[j] = b1[e0 + j];
#pragma unroll
  for (int k = 0; k < 4; ++k) {
    int tt = tl - 3 + k;
    if (tt >= 0) {
      short8 v = *reinterpret_cast<const short8*>(&xin[(size_t)(t - 3 + k) * 256 + e0]);
#pragma unroll
      for (int j = 0; j < 8; ++j) acc[j] += bfu2f((u16b)v[j]) * w1[(e0 + j) * 4 + k];
    }
  }
  short8 o;
#pragma unroll
  for (int j = 0; j < 8; ++j) {
    float s = acc[j] / (1.f + __expf(-acc[j]));  // SiLU
    o[j] = (short)f2bfu(s);
  }
  *reinterpret_cast<short8*>(&xconv[(size_t)t * 256 + e0]) = o;
}

// ---------------- x_proj fused with dt_proj: (BL,256)@(256,288) -> dt(sp,bf16) | B | C ----------------
__global__ __launch_bounds__(256) void k_xproj(
    const u16b* __restrict__ xconv, const u16b* __restrict__ Bsw, const float* __restrict__ dtb,
    u16b* __restrict__ dt, float* __restrict__ Bm, float* __restrict__ Cm) {
  __shared__ __align__(16) u16b a_lds[64 * 264];
  __shared__ __align__(16) u16b b_lds[32 * 48 * 8];
  f32x4 acc[3];
  const int t0 = blockIdx.x * 64, n0 = blockIdx.y * 48;
  gemm_core<256, 48>(xconv, Bsw, 288, t0, n0, a_lds, b_lds, acc);
  const int w = threadIdx.x >> 6, l = threadIdx.x & 63;
  const int rbase = t0 + w * 16 + (l >> 4) * 4, cb = n0 + (l & 15);
#pragma unroll
  for (int nt = 0; nt < 3; ++nt)
#pragma unroll
    for (int r = 0; r < 4; ++r) {
      int row = rbase + r, col = cb + nt * 16;
      float v = acc[nt][r];
      if (col < 256) {
        float val = v + dtb[col];
        float sp = (val > 20.f) ? val : log1pf(__expf(val));  // softplus
        dt[(size_t)row * 256 + col] = f2bfu(sp);
      } else if (col < 272) {
        Bm[(size_t)row * 16 + (col - 256)] = v;
      } else {
        Cm[(size_t)row * 16 + (col - 272)] = v;
      }
    }
}

// ---------------- selective scan pass1: thread owns channel e, 16 states in regs ----------------
__global__ __launch_bounds__(256) void k_scan1(
    const u16b* __restrict__ dt, const u16b* __restrict__ u, const float* __restrict__ Bm,
    const float* __restrict__ Al2, float* __restrict__ Pst, float* __restrict__ Hst) {
  __shared__ float b_s[LCH * DN];
  const int bid = blockIdx.x;                       // NB*NCHK = 512
  const int c = bid & (NCHK - 1), b = bid >> 7;
  const int e = threadIdx.x;
  const size_t base = (size_t)b * LSEQ + (size_t)c * LCH;
  for (int idx = threadIdx.x; idx < LCH * DN; idx += 256)
    b_s[idx] = Bm[(base + (idx >> 4)) * DN + (idx & 15)];
  __syncthreads();
  float coef[16], h[16], P[16];
  const f32x4* al = reinterpret_cast<const f32x4*>(&Al2[e * 16]);
#pragma unroll
  for (int q = 0; q < 4; ++q) {
    f32x4 cv = al[q];
#pragma unroll
    for (int j = 0; j < 4; ++j) { coef[q * 4 + j] = cv[j]; h[q * 4 + j] = 0.f; P[q * 4 + j] = 1.f; }
  }
#pragma unroll 4
  for (int t = 0; t < LCH; ++t) {
    float dtv = bfu2f(dt[(base + t) * DE + e]);
    float uv = bfu2f(u[(base + t) * DE + e]);
    float dtu = dtv * uv;
    const f32x4* bp = reinterpret_cast<const f32x4*>(&b_s[t * 16]);
    f32x4 bq[4] = {bp[0], bp[1], bp[2], bp[3]};
#pragma unroll
    for (int n = 0; n < 16; ++n) {
      float a = exp2f(dtv * coef[n]);
      h[n] = fmaf(a, h[n], dtu * bq[n >> 2][n & 3]);
      P[n] *= a;
    }
  }
  size_t o = (((size_t)b * NCHK + c) * DE + e) * DN;
#pragma unroll
  for (int q = 0; q < 4; ++q) {
    f32x4 pv{P[q * 4], P[q * 4 + 1], P[q * 4 + 2], P[q * 4 + 3]};
    f32x4 hv{h[q * 4], h[q * 4 + 1], h[q * 4 + 2], h[q * 4 + 3]};
    *reinterpret_cast<f32x4*>(&Pst[o + q * 4]) = pv;
    *reinterpret_cast<f32x4*>(&Hst[o + q * 4]) = hv;
  }
}

// ---------------- cross-chunk combine (sequential over NCHK chunks) ----------------
__global__ __launch_bounds__(256) void k_combine(
    const float* __restrict__ Pst, const float* __restrict__ Hst, float* __restrict__ Hin) {
  int idx = blockIdx.x * 256 + threadIdx.x;  // over NB*DE*DN = 16384
  int en = idx & (DE * DN - 1), b = idx >> 12;
  float h = 0.f;
  for (int c = 0; c < NCHK; ++c) {
    size_t o = ((size_t)b * NCHK + c) * (DE * DN) + en;
    Hin[o] = h;
    h = fmaf(Pst[o], h, Hst[o]);
  }
}

// ---------------- pass2: replay chunk from Hin; y = C·h + u*D; out yz = y*silu(z) ----------------
__global__ __launch_bounds__(256) void k_scan2(
    const u16b* __restrict__ dt, const u16b* __restrict__ u, const float* __restrict__ Bm,
    const float* __restrict__ Cm, const float* __restrict__ Al2, const float* __restrict__ Hin,
    const float* __restrict__ Dsk, const u16b* __restrict__ zbuf, u16b* __restrict__ yz) {
  __shared__ float b_s[LCH * DN], c_s[LCH * DN];
  const int bid = blockIdx.x;
  const int c = bid & (NCHK - 1), b = bid >> 7;
  const int e = threadIdx.x;
  const size_t base = (size_t)b * LSEQ + (size_t)c * LCH;
  for (int idx = threadIdx.x; idx < LCH * DN; idx += 256) {
    b_s[idx] = Bm[(base + (idx >> 4)) * DN + (idx & 15)];
    c_s[idx] = Cm[(base + (idx >> 4)) * DN + (idx & 15)];
  }
  __syncthreads();
  float coef[16], h[16];
  const f32x4* al = reinterpret_cast<const f32x4*>(&Al2[e * 16]);
  size_t o = (((size_t)b * NCHK + c) * DE + e) * DN;
#pragma unroll
  for (int q = 0; q < 4; ++q) {
    f32x4 cv = al[q];
    f32x4 hv = *reinterpret_cast<const f32x4*>(&Hin[o + q * 4]);
#pragma unroll
    for (int j = 0; j < 4; ++j) { coef[q * 4 + j] = cv[j]; h[q * 4 + j] = hv[j]; }
  }
  const float dskv = Dsk[e];
#pragma unroll 4
  for (int t = 0; t < LCH; ++t) {
    float dtv = bfu2f(dt[(base + t) * DE + e]);
    float uv = bfu2f(u[(base + t) * DE + e]);
    float dtu = dtv * uv;
    const f32x4* bp = reinterpret_cast<const f32x4*>(&b_s[t * 16]);
    const f32x4* cp = reinterpret_cast<const f32x4*>(&c_s[t * 16]);
    f32x4 bq[4] = {bp[0], bp[1], bp[2], bp[3]};
    f32x4 cq[4] = {cp[0], cp[1], cp[2], cp[3]};
    float y = 0.f;
#pragma unroll
    for (int n = 0; n < 16; ++n) {
      float a = exp2f(dtv * coef[n]);
      h[n] = fmaf(a, h[n], dtu * bq[n >> 2][n & 3]);
      y = fmaf(h[n], cq[n >> 2][n & 3], y);
    }
    y = fmaf(uv, dskv, y);
    float z = bfu2f(zbuf[(base + t) * DE + e]);
    float sz = z / (1.f + __expf(-z));
    yz[(base + t) * DE + e] = f2bfu(y * sz);
  }
}

// ---------------- out_proj + final residual combine ----------------
__global__ __launch_bounds__(256) void k_outproj(
    const u16b* __restrict__ yz, const u16b* __restrict__ Bsw, const float* __restrict__ ob,
    const float* __restrict__ x, const u16b* __restrict__ hconv, float* __restrict__ outp) {
  __shared__ __align__(16) u16b a_lds[64 * 264];
  __shared__ __align__(16) u16b b_lds[32 * 64 * 8];
  f32x4 acc[4];
  const int t0 = blockIdx.x * 64, n0 = blockIdx.y * 64;
  gemm_core<256, 64>(yz, Bsw, 128, t0, n0, a_lds, b_lds, acc);
  const int w = threadIdx.x >> 6, l = threadIdx.x & 63;
  const int rbase = t0 + w * 16 + (l >> 4) * 4, cb = n0 + (l & 15);
#pragma unroll
  for (int nt = 0; nt < 4; ++nt)
#pragma unroll
    for (int r = 0; r < 4; ++r) {
      int row = rbase + r, col = cb + nt * 16;
      size_t off = (size_t)row * 128 + col;
      float v = x[off] + 0.5f * (acc[nt][r] + ob[col]) + 0.5f * bfu2f(hconv[off]);
      outp[off] = v;
    }
}

// ---------------- host launch ----------------
extern "C" void kernel_launch(void* const* d_in, const int* in_sizes, int n_in,
                              void* d_out, int out_size, void* d_ws, size_t ws_size,
                              hipStream_t stream) {
  const float* x       = (const float*)d_in[0];
  const float* ln_g    = (const float*)d_in[1];
  const float* ln_b    = (const float*)d_in[2];
  const float* conv_w  = (const float*)d_in[3];
  const float* conv_b  = (const float*)d_in[4];
  const float* in_w    = (const float*)d_in[5];
  const float* in_b    = (const float*)d_in[6];
  const float* dw_w    = (const float*)d_in[7];
  const float* dw_b    = (const float*)d_in[8];
  const float* xp_w    = (const float*)d_in[9];
  const float* dt_w    = (const float*)d_in[10];
  const float* dt_b    = (const float*)d_in[11];
  const float* A_log   = (const float*)d_in[12];
  const float* Dskip   = (const float*)d_in[13];
  const float* out_w   = (const float*)d_in[14];
  const float* out_b   = (const float*)d_in[15];
  float* outp = (float*)d_out;

  char* ws = (char*)d_ws;
  size_t off = 0;
  auto alloc = [&](size_t bytes) { char* p = ws + off; off += bytes; return p; };
  float* Al2   = (float*)alloc(4096ull * 4);              // A * log2e
  float* M2    = (float*)alloc(65536ull * 4);             // Wx[:, :8] @ Wdt
  u16b* WcSw   = (u16b*)alloc(49152ull * 2);              // conv  [48][128][8]
  u16b* WiSw   = (u16b*)alloc(65536ull * 2);              // inprj [16][512][8]
  u16b* WxSw   = (u16b*)alloc(73728ull * 2);              // xproj [32][288][8]
  u16b* WoSw   = (u16b*)alloc(32768ull * 2);              // outprj[32][128][8]
  u16b* hbuf   = (u16b*)alloc((size_t)NTOK * 128 * 2);    // LN output
  u16b* hconv  = (u16b*)alloc((size_t)NTOK * 128 * 2);    // gelu(conv)
  u16b* xin    = (u16b*)alloc((size_t)NTOK * 256 * 2);    // dead after dwconv; aliased by Pst
  u16b* zbuf   = (u16b*)alloc((size_t)NTOK * 256 * 2);
  u16b* xconv  = (u16b*)alloc((size_t)NTOK * 256 * 2);    // u for scan
  u16b* dt     = (u16b*)alloc((size_t)NTOK * 256 * 2);    // softplus'd, bf16
  float* Bm    = (float*)alloc((size_t)NTOK * 16 * 4);
  float* Cm    = (float*)alloc((size_t)NTOK * 16 * 4);
  float* Pst   = (float*)xin;                             // alias: NB*NCHK*DE*DN*4 == NTOK*256*2 bytes
  float* Hst   = (float*)alloc((size_t)NB * NCHK * DE * DN * 4);
  float* Hin   = (float*)alloc((size_t)NB * NCHK * DE * DN * 4);
  u16b* yz     = (u16b*)alloc((size_t)NTOK * 256 * 2);
  (void)ws_size; (void)in_sizes; (void)n_in; (void)out_size;

  k_prep1<<<256, 256, 0, stream>>>(xp_w, dt_w, A_log, M2, Al2);
  k_prep2<<<108, 256, 0, stream>>>(conv_w, in_w, M2, xp_w, out_w, WcSw, WiSw, WxSw, WoSw);
  k_ln<<<NTOK / 4, 256, 0, stream>>>(x, ln_g, ln_b, hbuf);
  k_convgemm<<<dim3(NTOK / 64, 2), 256, 0, stream>>>(hbuf, WcSw, conv_b, hconv);
  k_inproj<<<dim3(NTOK / 64, 8), 256, 0, stream>>>(hbuf, WiSw, in_b, xin, zbuf);
  k_dwconv<<<(NTOK * 32) / 256, 256, 0, stream>>>(xin, dw_w, dw_b, xconv);
  k_xproj<<<dim3(NTOK / 64, 6), 256, 0, stream>>>(xconv, WxSw, dt_b, dt, Bm, Cm);
  k_scan1<<<NB * NCHK, 256, 0, stream>>>(dt, xconv, Bm, Al2, Pst, Hst);
  k_combine<<<64, 256, 0, stream>>>(Pst, Hst, Hin);
  k_scan2<<<NB * NCHK, 256, 0, stream>>>(dt, xconv, Bm, Cm, Al2, Hin, Dskip, zbuf, yz);
  k_outproj<<<dim3(NTOK / 64, 2), 256, 0, stream>>>(yz, WoSw, out_b, x, hconv, outp);
}

// Round 3
// 151.134 us; speedup vs baseline: 1.3891x; 1.1898x over previous
//
#include <hip/hip_runtime.h>
#include <hip/hip_bf16.h>
#include <math.h>

typedef __attribute__((ext_vector_type(8))) short short8;
typedef __attribute__((ext_vector_type(4))) float f32x4;
typedef unsigned short u16b;

#define DEV __device__ __forceinline__

static constexpr int NB = 4, LSEQ = 4096, DMODEL = 128, DE = 256, DN = 16;
static constexpr int NTOK = NB * LSEQ;              // 16384
static constexpr int LCH = 32, NCHK = LSEQ / LCH;   // 32-step chunks, 128/batch

DEV float bfu2f(u16b u) { union { unsigned int i; float f; } x; x.i = ((unsigned int)u) << 16; return x.f; }
DEV u16b f2bfu(float f) {
  union { float fv; unsigned int i; } x; x.fv = f;
  unsigned int r = x.i + 0x7fffu + ((x.i >> 16) & 1u);
  return (u16b)(r >> 16);
}

// ---------------- merged prep: weight massage + Al2 (deterministic, every call) ----------------
__global__ __launch_bounds__(256) void k_prep(
    const float* __restrict__ conv_w, const float* __restrict__ in_w,
    const float* __restrict__ xp, const float* __restrict__ dtw,
    const float* __restrict__ out_w, const float* __restrict__ A_log,
    u16b* __restrict__ Wc, u16b* __restrict__ Wi, u16b* __restrict__ Wx, u16b* __restrict__ Wo,
    float* __restrict__ Al2) {
  int tid = blockIdx.x * 256 + threadIdx.x;  // 31744 tasks
  short8 sv;
  if (tid < 6144) {            // conv Bmat: [48][128][8]; Bmat[kk*128+ci][co] = conv_w[co][ci][kk]
    int kg = tid >> 7, n = tid & 127;
#pragma unroll
    for (int j = 0; j < 8; ++j) {
      int kidx = kg * 8 + j, kk = kidx >> 7, ci = kidx & 127;
      sv[j] = (short)f2bfu(conv_w[(n * 128 + ci) * 3 + kk]);
    }
    *reinterpret_cast<short8*>(&Wc[(kg * 128 + n) * 8]) = sv;
  } else if (tid < 14336) {    // in_proj: [16][512][8]
    int t = tid - 6144; int kg = t >> 9, n = t & 511;
#pragma unroll
    for (int j = 0; j < 8; ++j) sv[j] = (short)f2bfu(in_w[(kg * 8 + j) * 512 + n]);
    *reinterpret_cast<short8*>(&Wi[(kg * 512 + n) * 8]) = sv;
  } else if (tid < 23552) {    // x_proj fused: [32][288][8]; cols<256 = Wx[:,:8]@Wdt inline, >=256 = Wx[:,8:40]
    int t = tid - 14336; int kg = t / 288, n = t % 288;
    if (n < 256) {
      float dreg[8];
#pragma unroll
      for (int r = 0; r < 8; ++r) dreg[r] = dtw[r * 256 + n];
#pragma unroll
      for (int j = 0; j < 8; ++j) {
        int k = kg * 8 + j;
        float acc = 0.f;
#pragma unroll
        for (int r = 0; r < 8; ++r) acc = fmaf(xp[k * 40 + r], dreg[r], acc);
        sv[j] = (short)f2bfu(acc);
      }
    } else {
#pragma unroll
      for (int j = 0; j < 8; ++j) sv[j] = (short)f2bfu(xp[(kg * 8 + j) * 40 + 8 + (n - 256)]);
    }
    *reinterpret_cast<short8*>(&Wx[(kg * 288 + n) * 8]) = sv;
  } else if (tid < 27648) {    // out_proj: [32][128][8]
    int t = tid - 23552; int kg = t >> 7, n = t & 127;
#pragma unroll
    for (int j = 0; j < 8; ++j) sv[j] = (short)f2bfu(out_w[(kg * 8 + j) * 128 + n]);
    *reinterpret_cast<short8*>(&Wo[(kg * 128 + n) * 8]) = sv;
  } else if (tid < 27648 + DE * DN) {
    int t = tid - 27648;
    Al2[t] = -expf(A_log[t]) * 1.44269504088896341f;  // A * log2(e)
  }
}

// ---------------- LayerNorm: one wave per token ----------------
__global__ __launch_bounds__(256) void k_ln(
    const float* __restrict__ x, const float* __restrict__ g, const float* __restrict__ b,
    u16b* __restrict__ h) {
  int wv = (blockIdx.x * 256 + threadIdx.x) >> 6;  // token
  int l = threadIdx.x & 63;
  float2 xv = *reinterpret_cast<const float2*>(&x[(size_t)wv * 128 + l * 2]);
  float s = xv.x + xv.y, s2 = xv.x * xv.x + xv.y * xv.y;
#pragma unroll
  for (int m = 1; m < 64; m <<= 1) { s += __shfl_xor(s, m, 64); s2 += __shfl_xor(s2, m, 64); }
  float mu = s * (1.f / 128.f);
  float var = s2 * (1.f / 128.f) - mu * mu;
  float inv = rsqrtf(var + 1e-5f);
  u16b o0 = f2bfu((xv.x - mu) * inv * g[l * 2] + b[l * 2]);
  u16b o1 = f2bfu((xv.y - mu) * inv * g[l * 2 + 1] + b[l * 2 + 1]);
  u16b* hp = &h[(size_t)wv * 128 + l * 2];
  hp[0] = o0; hp[1] = o1;
}

// ---------------- generic MFMA core: BM=64 rows x BN cols, A row-major (stride K), B pre-swizzled [K/8][Ntot][8]
template <int K, int BN>
DEV void gemm_core(const u16b* __restrict__ Asrc, const u16b* __restrict__ Bsw, int Ntot,
                   int t0, int n0, u16b* a_lds, u16b* b_lds, f32x4* acc) {
  constexpr int LDA = K + 8;
  const int tid = threadIdx.x;
  for (int idx = tid; idx < 64 * (K / 8); idx += 256) {
    int r = idx / (K / 8), kc = idx % (K / 8);
    *reinterpret_cast<uint4*>(&a_lds[r * LDA + kc * 8]) =
        *reinterpret_cast<const uint4*>(&Asrc[(size_t)(t0 + r) * K + kc * 8]);
  }
  for (int idx = tid; idx < (K / 8) * BN; idx += 256) {
    int kg = idx / BN, nn = idx % BN;
    *reinterpret_cast<uint4*>(&b_lds[(kg * BN + nn) * 8]) =
        *reinterpret_cast<const uint4*>(&Bsw[((size_t)kg * Ntot + n0 + nn) * 8]);
  }
  __syncthreads();
  const int w = tid >> 6, l = tid & 63;
  const int lr = l & 15, lk = l >> 4;
#pragma unroll
  for (int nt = 0; nt < BN / 16; ++nt) acc[nt] = f32x4{0.f, 0.f, 0.f, 0.f};
#pragma unroll
  for (int c = 0; c < K / 32; ++c) {
    short8 af = *reinterpret_cast<const short8*>(&a_lds[(w * 16 + lr) * LDA + c * 32 + lk * 8]);
#pragma unroll
    for (int nt = 0; nt < BN / 16; ++nt) {
      short8 bf = *reinterpret_cast<const short8*>(&b_lds[((c * 4 + lk) * BN + nt * 16 + lr) * 8]);
      acc[nt] = __builtin_amdgcn_mfma_f32_16x16x32_bf16(af, bf, acc[nt], 0, 0, 0);
    }
  }
}

// ---------------- block conv (K=3, full 128x128) as GEMM over haloed h tile + exact GELU ----------------
__global__ __launch_bounds__(256) void k_convgemm(
    const u16b* __restrict__ h, const u16b* __restrict__ Bsw,
    const float* __restrict__ convb, u16b* __restrict__ hconv) {
  __shared__ __align__(16) u16b h_lds[66 * 136];
  __shared__ __align__(16) u16b b_lds[48 * 64 * 8];
  const int t0 = blockIdx.x * 64, n0 = blockIdx.y * 64;
  const int tl0 = t0 & (LSEQ - 1);
  const int tid = threadIdx.x;
  for (int idx = tid; idx < 66 * 16; idx += 256) {  // rows t0-2 .. t0+63
    int r = idx >> 4, kc = idx & 15;
    uint4 v = make_uint4(0u, 0u, 0u, 0u);
    if (tl0 + r - 2 >= 0)
      v = *reinterpret_cast<const uint4*>(&h[(size_t)(t0 + r - 2) * 128 + kc * 8]);
    *reinterpret_cast<uint4*>(&h_lds[r * 136 + kc * 8]) = v;
  }
  for (int idx = tid; idx < 48 * 64; idx += 256) {
    int kg = idx >> 6, nn = idx & 63;
    *reinterpret_cast<uint4*>(&b_lds[(kg * 64 + nn) * 8]) =
        *reinterpret_cast<const uint4*>(&Bsw[((size_t)kg * 128 + n0 + nn) * 8]);
  }
  __syncthreads();
  const int w = tid >> 6, l = tid & 63, lr = l & 15, lk = l >> 4;
  f32x4 acc[4];
#pragma unroll
  for (int nt = 0; nt < 4; ++nt) acc[nt] = f32x4{0.f, 0.f, 0.f, 0.f};
#pragma unroll
  for (int c = 0; c < 12; ++c) {
    int kk = c >> 2, ci0 = (c & 3) * 32;
    short8 af = *reinterpret_cast<const short8*>(&h_lds[(w * 16 + lr + kk) * 136 + ci0 + lk * 8]);
#pragma unroll
    for (int nt = 0; nt < 4; ++nt) {
      short8 bf = *reinterpret_cast<const short8*>(&b_lds[((c * 4 + lk) * 64 + nt * 16 + lr) * 8]);
      acc[nt] = __builtin_amdgcn_mfma_f32_16x16x32_bf16(af, bf, acc[nt], 0, 0, 0);
    }
  }
  const int rbase = t0 + w * 16 + lk * 4, cb = n0 + lr;
#pragma unroll
  for (int nt = 0; nt < 4; ++nt)
#pragma unroll
    for (int r = 0; r < 4; ++r) {
      int row = rbase + r, col = cb + nt * 16;
      float v = acc[nt][r] + convb[col];
      float gel = 0.5f * v * (1.f + erff(v * 0.70710678118654752f));
      hconv[(size_t)row * 128 + col] = f2bfu(gel);
    }
}

// ---------------- in_proj: (BL,128)@(128,512), BN=128, split x_in / z ----------------
__global__ __launch_bounds__(256) void k_inproj(
    const u16b* __restrict__ h, const u16b* __restrict__ Bsw, const float* __restrict__ bias,
    u16b* __restrict__ xin, u16b* __restrict__ zbuf) {
  __shared__ __align__(16) u16b a_lds[64 * 136];
  __shared__ __align__(16) u16b b_lds[16 * 128 * 8];
  f32x4 acc[8];
  const int t0 = blockIdx.x * 64, n0 = blockIdx.y * 128;
  gemm_core<128, 128>(h, Bsw, 512, t0, n0, a_lds, b_lds, acc);
  const int w = threadIdx.x >> 6, l = threadIdx.x & 63;
  const int rbase = t0 + w * 16 + (l >> 4) * 4, cb = n0 + (l & 15);
#pragma unroll
  for (int nt = 0; nt < 8; ++nt)
#pragma unroll
    for (int r = 0; r < 4; ++r) {
      int row = rbase + r, col = cb + nt * 16;
      float v = acc[nt][r] + bias[col];
      if (col < 256) xin[(size_t)row * 256 + col] = f2bfu(v);
      else zbuf[(size_t)row * 256 + (col - 256)] = f2bfu(v);
    }
}

// ---------------- depthwise causal conv (k=4) + SiLU: 8 ch x 8 tokens per thread, rolling window ----------------
__global__ __launch_bounds__(256) void k_dwconv(
    const u16b* __restrict__ xin, const float* __restrict__ w1, const float* __restrict__ b1,
    u16b* __restrict__ xconv) {
  int tid = blockIdx.x * 256 + threadIdx.x;      // 65536 = NTOK/8 * 32
  int eg = tid & 31, tbase = (tid >> 5) * 8;
  int e0 = eg * 8;
  float wreg[4][8], breg[8];
#pragma unroll
  for (int j = 0; j < 8; ++j) {
    breg[j] = b1[e0 + j];
#pragma unroll
    for (int k = 0; k < 4; ++k) wreg[k][j] = w1[(e0 + j) * 4 + k];
  }
  float win[4][8];
  const int tl0 = tbase & (LSEQ - 1);
#pragma unroll
  for (int k = 0; k < 4; ++k) {                  // rows tbase-3 .. tbase
    if (tl0 + k - 3 >= 0) {
      short8 v = *reinterpret_cast<const short8*>(&xin[(size_t)(tbase - 3 + k) * 256 + e0]);
#pragma unroll
      for (int j = 0; j < 8; ++j) win[k][j] = bfu2f((u16b)v[j]);
    } else {
#pragma unroll
      for (int j = 0; j < 8; ++j) win[k][j] = 0.f;
    }
  }
#pragma unroll
  for (int tt = 0; tt < 8; ++tt) {
    int t = tbase + tt;
    if (tt) {
      short8 v = *reinterpret_cast<const short8*>(&xin[(size_t)t * 256 + e0]);
#pragma unroll
      for (int j = 0; j < 8; ++j) win[3][j] = bfu2f((u16b)v[j]);
    }
    short8 o;
#pragma unroll
    for (int j = 0; j < 8; ++j) {
      float acc = breg[j];
#pragma unroll
      for (int k = 0; k < 4; ++k) acc = fmaf(win[k][j], wreg[k][j], acc);
      float s = acc / (1.f + __expf(-acc));  // SiLU
      o[j] = (short)f2bfu(s);
    }
    *reinterpret_cast<short8*>(&xconv[(size_t)t * 256 + e0]) = o;
#pragma unroll
    for (int k = 0; k < 3; ++k)
#pragma unroll
      for (int j = 0; j < 8; ++j) win[k][j] = win[k + 1][j];
  }
}

// ---------------- x_proj fused with dt_proj: (BL,256)@(256,288) -> dt(sp,bf16) | B | C ----------------
__global__ __launch_bounds__(256) void k_xproj(
    const u16b* __restrict__ xconv, const u16b* __restrict__ Bsw, const float* __restrict__ dtb,
    u16b* __restrict__ dt, float* __restrict__ Bm, float* __restrict__ Cm) {
  __shared__ __align__(16) u16b a_lds[64 * 264];
  __shared__ __align__(16) u16b b_lds[32 * 48 * 8];
  f32x4 acc[3];
  const int t0 = blockIdx.x * 64, n0 = blockIdx.y * 48;
  gemm_core<256, 48>(xconv, Bsw, 288, t0, n0, a_lds, b_lds, acc);
  const int w = threadIdx.x >> 6, l = threadIdx.x & 63;
  const int rbase = t0 + w * 16 + (l >> 4) * 4, cb = n0 + (l & 15);
#pragma unroll
  for (int nt = 0; nt < 3; ++nt)
#pragma unroll
    for (int r = 0; r < 4; ++r) {
      int row = rbase + r, col = cb + nt * 16;
      float v = acc[nt][r];
      if (col < 256) {
        float val = v + dtb[col];
        float sp = (val > 20.f) ? val : log1pf(__expf(val));  // softplus
        dt[(size_t)row * 256 + col] = f2bfu(sp);
      } else if (col < 272) {
        Bm[(size_t)row * 16 + (col - 256)] = v;
      } else {
        Cm[(size_t)row * 16 + (col - 272)] = v;
      }
    }
}

// ---------------- selective scan pass1: thread owns channel e, 16 states in regs ----------------
__global__ __launch_bounds__(256) void k_scan1(
    const u16b* __restrict__ dt, const u16b* __restrict__ u, const float* __restrict__ Bm,
    const float* __restrict__ Al2, float* __restrict__ Pst, float* __restrict__ Hst) {
  __shared__ float b_s[LCH * DN];
  const int bid = blockIdx.x;                       // NB*NCHK = 512
  const int c = bid & (NCHK - 1), b = bid >> 7;
  const int e = threadIdx.x;
  const size_t base = (size_t)b * LSEQ + (size_t)c * LCH;
  for (int idx = threadIdx.x; idx < LCH * DN; idx += 256)
    b_s[idx] = Bm[(base + (idx >> 4)) * DN + (idx & 15)];
  __syncthreads();
  float coef[16], h[16], P[16];
  const f32x4* al = reinterpret_cast<const f32x4*>(&Al2[e * 16]);
#pragma unroll
  for (int q = 0; q < 4; ++q) {
    f32x4 cv = al[q];
#pragma unroll
    for (int j = 0; j < 4; ++j) { coef[q * 4 + j] = cv[j]; h[q * 4 + j] = 0.f; P[q * 4 + j] = 1.f; }
  }
#pragma unroll 4
  for (int t = 0; t < LCH; ++t) {
    float dtv = bfu2f(dt[(base + t) * DE + e]);
    float uv = bfu2f(u[(base + t) * DE + e]);
    float dtu = dtv * uv;
    const f32x4* bp = reinterpret_cast<const f32x4*>(&b_s[t * 16]);
    f32x4 bq[4] = {bp[0], bp[1], bp[2], bp[3]};
#pragma unroll
    for (int n = 0; n < 16; ++n) {
      float a = exp2f(dtv * coef[n]);
      h[n] = fmaf(a, h[n], dtu * bq[n >> 2][n & 3]);
      P[n] *= a;
    }
  }
  size_t o = (((size_t)b * NCHK + c) * DE + e) * DN;
#pragma unroll
  for (int q = 0; q < 4; ++q) {
    f32x4 pv{P[q * 4], P[q * 4 + 1], P[q * 4 + 2], P[q * 4 + 3]};
    f32x4 hv{h[q * 4], h[q * 4 + 1], h[q * 4 + 2], h[q * 4 + 3]};
    *reinterpret_cast<f32x4*>(&Pst[o + q * 4]) = pv;
    *reinterpret_cast<f32x4*>(&Hst[o + q * 4]) = hv;
  }
}

// ---------------- cross-chunk combine: batched loads, 16-step groups ----------------
__global__ __launch_bounds__(256) void k_combine(
    const float* __restrict__ Pst, const float* __restrict__ Hst, float* __restrict__ Hin) {
  int idx = blockIdx.x * 256 + threadIdx.x;  // over NB*DE*DN = 16384
  int en = idx & (DE * DN - 1), b = idx >> 12;
  size_t base = (size_t)b * NCHK * (DE * DN) + en;
  float h = 0.f;
  for (int c0 = 0; c0 < NCHK; c0 += 16) {
    float P[16], H[16];
#pragma unroll
    for (int j = 0; j < 16; ++j) {
      size_t o = base + (size_t)(c0 + j) * (DE * DN);
      P[j] = Pst[o]; H[j] = Hst[o];
    }
#pragma unroll
    for (int j = 0; j < 16; ++j) {
      size_t o = base + (size_t)(c0 + j) * (DE * DN);
      Hin[o] = h;
      h = fmaf(P[j], h, H[j]);
    }
  }
}

// ---------------- pass2: replay chunk from Hin; y = C·h + u*D; out yz = y*silu(z) ----------------
__global__ __launch_bounds__(256) void k_scan2(
    const u16b* __restrict__ dt, const u16b* __restrict__ u, const float* __restrict__ Bm,
    const float* __restrict__ Cm, const float* __restrict__ Al2, const float* __restrict__ Hin,
    const float* __restrict__ Dsk, const u16b* __restrict__ zbuf, u16b* __restrict__ yz) {
  __shared__ float b_s[LCH * DN], c_s[LCH * DN];
  const int bid = blockIdx.x;
  const int c = bid & (NCHK - 1), b = bid >> 7;
  const int e = threadIdx.x;
  const size_t base = (size_t)b * LSEQ + (size_t)c * LCH;
  for (int idx = threadIdx.x; idx < LCH * DN; idx += 256) {
    b_s[idx] = Bm[(base + (idx >> 4)) * DN + (idx & 15)];
    c_s[idx] = Cm[(base + (idx >> 4)) * DN + (idx & 15)];
  }
  __syncthreads();
  float coef[16], h[16];
  const f32x4* al = reinterpret_cast<const f32x4*>(&Al2[e * 16]);
  size_t o = (((size_t)b * NCHK + c) * DE + e) * DN;
#pragma unroll
  for (int q = 0; q < 4; ++q) {
    f32x4 cv = al[q];
    f32x4 hv = *reinterpret_cast<const f32x4*>(&Hin[o + q * 4]);
#pragma unroll
    for (int j = 0; j < 4; ++j) { coef[q * 4 + j] = cv[j]; h[q * 4 + j] = hv[j]; }
  }
  const float dskv = Dsk[e];
#pragma unroll 4
  for (int t = 0; t < LCH; ++t) {
    float dtv = bfu2f(dt[(base + t) * DE + e]);
    float uv = bfu2f(u[(base + t) * DE + e]);
    float dtu = dtv * uv;
    const f32x4* bp = reinterpret_cast<const f32x4*>(&b_s[t * 16]);
    const f32x4* cp = reinterpret_cast<const f32x4*>(&c_s[t * 16]);
    f32x4 bq[4] = {bp[0], bp[1], bp[2], bp[3]};
    f32x4 cq[4] = {cp[0], cp[1], cp[2], cp[3]};
    float y = 0.f;
#pragma unroll
    for (int n = 0; n < 16; ++n) {
      float a = exp2f(dtv * coef[n]);
      h[n] = fmaf(a, h[n], dtu * bq[n >> 2][n & 3]);
      y = fmaf(h[n], cq[n >> 2][n & 3], y);
    }
    y = fmaf(uv, dskv, y);
    float z = bfu2f(zbuf[(base + t) * DE + e]);
    float sz = z / (1.f + __expf(-z));
    yz[(base + t) * DE + e] = f2bfu(y * sz);
  }
}

// ---------------- out_proj + final residual combine ----------------
__global__ __launch_bounds__(256) void k_outproj(
    const u16b* __restrict__ yz, const u16b* __restrict__ Bsw, const float* __restrict__ ob,
    const float* __restrict__ x, const u16b* __restrict__ hconv, float* __restrict__ outp) {
  __shared__ __align__(16) u16b a_lds[64 * 264];
  __shared__ __align__(16) u16b b_lds[32 * 64 * 8];
  f32x4 acc[4];
  const int t0 = blockIdx.x * 64, n0 = blockIdx.y * 64;
  gemm_core<256, 64>(yz, Bsw, 128, t0, n0, a_lds, b_lds, acc);
  const int w = threadIdx.x >> 6, l = threadIdx.x & 63;
  const int rbase = t0 + w * 16 + (l >> 4) * 4, cb = n0 + (l & 15);
#pragma unroll
  for (int nt = 0; nt < 4; ++nt)
#pragma unroll
    for (int r = 0; r < 4; ++r) {
      int row = rbase + r, col = cb + nt * 16;
      size_t off = (size_t)row * 128 + col;
      float v = x[off] + 0.5f * (acc[nt][r] + ob[col]) + 0.5f * bfu2f(hconv[off]);
      outp[off] = v;
    }
}

// ---------------- host launch ----------------
extern "C" void kernel_launch(void* const* d_in, const int* in_sizes, int n_in,
                              void* d_out, int out_size, void* d_ws, size_t ws_size,
                              hipStream_t stream) {
  const float* x       = (const float*)d_in[0];
  const float* ln_g    = (const float*)d_in[1];
  const float* ln_b    = (const float*)d_in[2];
  const float* conv_w  = (const float*)d_in[3];
  const float* conv_b  = (const float*)d_in[4];
  const float* in_w    = (const float*)d_in[5];
  const float* in_b    = (const float*)d_in[6];
  const float* dw_w    = (const float*)d_in[7];
  const float* dw_b    = (const float*)d_in[8];
  const float* xp_w    = (const float*)d_in[9];
  const float* dt_w    = (const float*)d_in[10];
  const float* dt_b    = (const float*)d_in[11];
  const float* A_log   = (const float*)d_in[12];
  const float* Dskip   = (const float*)d_in[13];
  const float* out_w   = (const float*)d_in[14];
  const float* out_b   = (const float*)d_in[15];
  float* outp = (float*)d_out;

  char* ws = (char*)d_ws;
  size_t off = 0;
  auto alloc = [&](size_t bytes) { char* p = ws + off; off += bytes; return p; };
  float* Al2   = (float*)alloc(4096ull * 4);              // A * log2e
  u16b* WcSw   = (u16b*)alloc(49152ull * 2);              // conv  [48][128][8]
  u16b* WiSw   = (u16b*)alloc(65536ull * 2);              // inprj [16][512][8]
  u16b* WxSw   = (u16b*)alloc(73728ull * 2);              // xproj [32][288][8]
  u16b* WoSw   = (u16b*)alloc(32768ull * 2);              // outprj[32][128][8]
  u16b* hbuf   = (u16b*)alloc((size_t)NTOK * 128 * 2);    // LN output
  u16b* hconv  = (u16b*)alloc((size_t)NTOK * 128 * 2);    // gelu(conv)
  u16b* xin    = (u16b*)alloc((size_t)NTOK * 256 * 2);    // dead after dwconv; aliased by Pst
  u16b* zbuf   = (u16b*)alloc((size_t)NTOK * 256 * 2);
  u16b* xconv  = (u16b*)alloc((size_t)NTOK * 256 * 2);    // u for scan
  u16b* dt     = (u16b*)alloc((size_t)NTOK * 256 * 2);    // softplus'd, bf16
  float* Bm    = (float*)alloc((size_t)NTOK * 16 * 4);
  float* Cm    = (float*)alloc((size_t)NTOK * 16 * 4);
  float* Pst   = (float*)xin;                             // alias: NB*NCHK*DE*DN*4 == NTOK*256*2 bytes
  float* Hst   = (float*)alloc((size_t)NB * NCHK * DE * DN * 4);
  float* Hin   = (float*)alloc((size_t)NB * NCHK * DE * DN * 4);
  u16b* yz     = (u16b*)alloc((size_t)NTOK * 256 * 2);
  (void)ws_size; (void)in_sizes; (void)n_in; (void)out_size;

  k_prep<<<124, 256, 0, stream>>>(conv_w, in_w, xp_w, dt_w, out_w, A_log,
                                  WcSw, WiSw, WxSw, WoSw, Al2);
  k_ln<<<NTOK / 4, 256, 0, stream>>>(x, ln_g, ln_b, hbuf);
  k_convgemm<<<dim3(NTOK / 64, 2), 256, 0, stream>>>(hbuf, WcSw, conv_b, hconv);
  k_inproj<<<dim3(NTOK / 64, 4), 256, 0, stream>>>(hbuf, WiSw, in_b, xin, zbuf);
  k_dwconv<<<256, 256, 0, stream>>>(xin, dw_w, dw_b, xconv);
  k_xproj<<<dim3(NTOK / 64, 6), 256, 0, stream>>>(xconv, WxSw, dt_b, dt, Bm, Cm);
  k_scan1<<<NB * NCHK, 256, 0, stream>>>(dt, xconv, Bm, Al2, Pst, Hst);
  k_combine<<<64, 256, 0, stream>>>(Pst, Hst, Hin);
  k_scan2<<<NB * NCHK, 256, 0, stream>>>(dt, xconv, Bm, Cm, Al2, Hin, Dskip, zbuf, yz);
  k_outproj<<<dim3(NTOK / 64, 2), 256, 0, stream>>>(yz, WoSw, out_b, x, hconv, outp);
}